// Round 4
// baseline (504.634 us; speedup 1.0000x reference)
//
#include <hip/hip_runtime.h>
#include <math.h>

// ---------------------------------------------------------------------------
// SplineConv GNN: 3 layers (in=2->16, 16->16, 16->16), K=5 per dim (dim=2),
// degree-1 open B-spline, mean aggregation, root weight + bias, ReLU.
// Final: FC [16,1] + bias + sigmoid -> out[N] f32.
//
// Round 4: edge16 was LDS-byte-bound (16x ds_read_b128/thread ~ 125us/CU).
//  - W staged in LDS as bf16: 2x ds_read_b128 per tap (halves LDS bytes),
//    LDS 19.6KB -> occupancy cap 100%.
//  - pack stores exact f32 (f0,f1); basis products recomputed (6 VALU) ->
//    only error source is W bf16 (validated in round 2: absmax 0.0039).
//  - atomic mapping unchanged (16 threads/edge, channel-contiguous lanes).
// ---------------------------------------------------------------------------

#define KS 5

#define BF2F_LO(u) __uint_as_float((u) << 16)
#define BF2F_HI(u) __uint_as_float((u) & 0xffff0000u)

// ---- degree count -----------------------------------------------------------
__global__ void deg_count_kernel(const int* __restrict__ dst, float* __restrict__ deg, int E) {
    int stride = gridDim.x * blockDim.x;
    for (int e = blockIdx.x * blockDim.x + threadIdx.x; e < E; e += stride) {
        atomicAdd(&deg[dst[e]], 1.0f);
    }
}

__global__ void deg_inv_kernel(float* __restrict__ deg, int N) {
    int i = blockIdx.x * blockDim.x + threadIdx.x;
    if (i < N) deg[i] = 1.0f / fmaxf(deg[i], 1.0f);
}

// ---- per-edge basis precompute ---------------------------------------------
// pack = { wi0|wi1<<8|wi2<<16|wi3<<24, f32(f0), f32(f1), src }
__global__ void pack_kernel(const float* __restrict__ eattr, const int* __restrict__ src,
                            uint4* __restrict__ pack, int E) {
    int stride = gridDim.x * blockDim.x;
    for (int e = blockIdx.x * blockDim.x + threadIdx.x; e < E; e += stride) {
        float2 ea = reinterpret_cast<const float2*>(eattr)[e];
        float a0 = ea.x * (float)(KS - 1);
        float a1 = ea.y * (float)(KS - 1);
        float k0 = fminf(fmaxf(floorf(a0), 0.0f), (float)(KS - 2));
        float k1 = fminf(fmaxf(floorf(a1), 0.0f), (float)(KS - 2));
        float f0 = a0 - k0, f1 = a1 - k1;
        int i0 = (int)k0, i1 = (int)k1;
        int w00 = i0 + KS * i1;
        unsigned wis = (unsigned)w00 | ((unsigned)(w00 + 1) << 8) |
                       ((unsigned)(w00 + KS) << 16) | ((unsigned)(w00 + KS + 1) << 24);
        pack[e] = make_uint4(wis, __float_as_uint(f0), __float_as_uint(f1), (unsigned)src[e]);
    }
}

__device__ __forceinline__ void decode_or_compute(
        bool haspack, const uint4* pack, const float* eattr, const int* srcp,
        int e, int& s, float b[4], int wi[4]) {
    float f0, f1;
    if (haspack) {
        uint4 pk = pack[e];
        s = (int)pk.w;
        wi[0] = (int)(pk.x & 255); wi[1] = (int)((pk.x >> 8) & 255);
        wi[2] = (int)((pk.x >> 16) & 255); wi[3] = (int)(pk.x >> 24);
        f0 = __uint_as_float(pk.y);
        f1 = __uint_as_float(pk.z);
    } else {
        float2 ea = reinterpret_cast<const float2*>(eattr)[e];
        float a0 = ea.x * (float)(KS - 1);
        float a1 = ea.y * (float)(KS - 1);
        float k0 = fminf(fmaxf(floorf(a0), 0.0f), (float)(KS - 2));
        float k1 = fminf(fmaxf(floorf(a1), 0.0f), (float)(KS - 2));
        f0 = a0 - k0; f1 = a1 - k1;
        int i0 = (int)k0, i1 = (int)k1;
        int w00 = i0 + KS * i1;
        wi[0] = w00; wi[1] = w00 + 1; wi[2] = w00 + KS; wi[3] = w00 + KS + 1;
        s = srcp[e];
    }
    float g0 = 1.0f - f0, g1 = 1.0f - f1;
    b[0] = g0 * g1; b[1] = f0 * g1; b[2] = g0 * f1; b[3] = f0 * f1;
}

// ---- edge kernels -----------------------------------------------------------
// 16 threads per edge, o = t & 15. Grid-stride.
// LDS (bf16): row(k,o) at dword offset k*196 + o*12, 16 bf16 (32B) per row.
// Row starts 16B-aligned (196 and 12 both multiples of 4 dwords).
template <bool HASPACK>
__global__ __launch_bounds__(256) void edge16_kernel(
        const float* __restrict__ h,      // [N,16]
        const int* __restrict__ dst,
        const uint4* __restrict__ pack,   // [E] (if HASPACK)
        const float* __restrict__ eattr,  // [E,2] (if !HASPACK)
        const int* __restrict__ srcp,     // [E]   (if !HASPACK)
        const float* __restrict__ W,      // [25,16,16]
        float* __restrict__ agg,          // [N,16] zeroed
        int E) {
    __shared__ unsigned Wl[25 * 196];     // bf16 pairs, 19.6 KB
    for (int idx = threadIdx.x; idx < 25 * 256; idx += blockDim.x) {
        int k = idx >> 8;
        int r = idx & 255;
        int i = r >> 4;
        int o = r & 15;
        unsigned u = __float_as_uint(W[idx]);
        unsigned bf = (u + 0x7fffu + ((u >> 16) & 1u)) >> 16;  // RNE to bf16
        reinterpret_cast<ushort*>(Wl)[(k * 196 + o * 12) * 2 + i] = (ushort)bf;
    }
    __syncthreads();

    int gs = gridDim.x * blockDim.x;
    int total = E * 16;
    for (int t = blockIdx.x * blockDim.x + threadIdx.x; t < total; t += gs) {
        int e = t >> 4;
        int o = t & 15;
        int s;
        float b[4];
        int wi[4];
        decode_or_compute(HASPACK, pack, eattr, srcp, e, s, b, wi);

        const float4* h4 = reinterpret_cast<const float4*>(h + (size_t)s * 16);
        float4 h0 = h4[0], h1 = h4[1], h2 = h4[2], h3 = h4[3];

        float acc = 0.0f;
        #pragma unroll
        for (int sp = 0; sp < 4; ++sp) {
            const unsigned* wp = &Wl[wi[sp] * 196 + o * 12];
            uint4 wa = *reinterpret_cast<const uint4*>(wp);      // i=0..7
            uint4 wb = *reinterpret_cast<const uint4*>(wp + 4);  // i=8..15
            float p;
            p  = h0.x * BF2F_LO(wa.x) + h0.y * BF2F_HI(wa.x)
               + h0.z * BF2F_LO(wa.y) + h0.w * BF2F_HI(wa.y)
               + h1.x * BF2F_LO(wa.z) + h1.y * BF2F_HI(wa.z)
               + h1.z * BF2F_LO(wa.w) + h1.w * BF2F_HI(wa.w)
               + h2.x * BF2F_LO(wb.x) + h2.y * BF2F_HI(wb.x)
               + h2.z * BF2F_LO(wb.y) + h2.w * BF2F_HI(wb.y)
               + h3.x * BF2F_LO(wb.z) + h3.y * BF2F_HI(wb.z)
               + h3.z * BF2F_LO(wb.w) + h3.w * BF2F_HI(wb.w);
            acc += b[sp] * p;
        }
        atomicAdd(&agg[(size_t)dst[e] * 16 + o], acc);
    }
}

template <bool HASPACK>
__global__ __launch_bounds__(256) void edge2_kernel(
        const float* __restrict__ x,      // [N,2]
        const int* __restrict__ dst,
        const uint4* __restrict__ pack,
        const float* __restrict__ eattr,
        const int* __restrict__ srcp,
        const float* __restrict__ W,      // [25,2,16]
        float* __restrict__ agg,          // [N,16] zeroed
        int E) {
    // Wl[k][o][i] row stride 6 floats (24B, 8B-aligned), k stride 96 floats.
    __shared__ float Wl[25 * 96];
    for (int idx = threadIdx.x; idx < 25 * 32; idx += blockDim.x) {
        int k = idx >> 5;
        int r = idx & 31;
        int i = r >> 4;
        int o = r & 15;
        Wl[k * 96 + o * 6 + i] = W[idx];
    }
    __syncthreads();

    int gs = gridDim.x * blockDim.x;
    int total = E * 16;
    for (int t = blockIdx.x * blockDim.x + threadIdx.x; t < total; t += gs) {
        int e = t >> 4;
        int o = t & 15;
        int s;
        float b[4];
        int wi[4];
        decode_or_compute(HASPACK, pack, eattr, srcp, e, s, b, wi);

        float2 xv = reinterpret_cast<const float2*>(x)[s];

        float acc = 0.0f;
        #pragma unroll
        for (int sp = 0; sp < 4; ++sp) {
            float2 w = *reinterpret_cast<const float2*>(&Wl[wi[sp] * 96 + o * 6]);
            acc += b[sp] * (xv.x * w.x + xv.y * w.y);
        }
        atomicAdd(&agg[(size_t)dst[e] * 16 + o], acc);
    }
}

// ---- finalize: out = relu(agg * invdeg + hin @ root + bias) ----------------
template <int IN>
__global__ void finalize_kernel(const float* __restrict__ hin,    // [N, IN]
                                const float* __restrict__ root,   // [IN, 16]
                                const float* __restrict__ bias,   // [16]
                                const float* __restrict__ invdeg, // [N]
                                float* __restrict__ h,            // [N,16] in: agg / out: act
                                int N) {
    int t = blockIdx.x * blockDim.x + threadIdx.x;
    if (t >= N * 16) return;
    int o = t & 15;
    int n = t >> 4;
    float acc = h[t] * invdeg[n];
    #pragma unroll
    for (int i = 0; i < IN; ++i) acc += hin[(size_t)n * IN + i] * root[i * 16 + o];
    acc += bias[o];
    h[t] = fmaxf(acc, 0.0f);
}

// ---- final FC + sigmoid ----------------------------------------------------
__global__ void fc_kernel(const float* __restrict__ h,   // [N,16]
                          const float* __restrict__ fcw, // [16]
                          const float* __restrict__ fcb, // [1]
                          float* __restrict__ out, int N) {
    int n = blockIdx.x * blockDim.x + threadIdx.x;
    if (n >= N) return;
    const float4* h4 = reinterpret_cast<const float4*>(h + (size_t)n * 16);
    float acc = fcb[0];
    #pragma unroll
    for (int q = 0; q < 4; ++q) {
        float4 v = h4[q];
        acc += v.x * fcw[4 * q + 0] + v.y * fcw[4 * q + 1] +
               v.z * fcw[4 * q + 2] + v.w * fcw[4 * q + 3];
    }
    out[n] = 1.0f / (1.0f + expf(-acc));
}

extern "C" void kernel_launch(void* const* d_in, const int* in_sizes, int n_in,
                              void* d_out, int out_size, void* d_ws, size_t ws_size,
                              hipStream_t stream) {
    const float* x      = (const float*)d_in[0];   // [N,2]
    const int*   eidx   = (const int*)d_in[1];     // [2,E]
    const float* eattr  = (const float*)d_in[2];   // [E,2]
    const float* W1     = (const float*)d_in[3];
    const float* root1  = (const float*)d_in[4];
    const float* b1     = (const float*)d_in[5];
    const float* W2     = (const float*)d_in[6];
    const float* root2  = (const float*)d_in[7];
    const float* b2     = (const float*)d_in[8];
    const float* W3     = (const float*)d_in[9];
    const float* root3  = (const float*)d_in[10];
    const float* b3     = (const float*)d_in[11];
    const float* fcw    = (const float*)d_in[12];
    const float* fcb    = (const float*)d_in[13];
    float* out = (float*)d_out;

    const int N = in_sizes[0] / 2;
    const int E = in_sizes[2] / 2;
    const int* src = eidx;
    const int* dst = eidx + E;

    float* hA  = (float*)d_ws;            // [N,16]
    float* hB  = hA + (size_t)N * 16;     // [N,16]
    float* deg = hB + (size_t)N * 16;     // [N]
    // pack buffer after deg, 16B aligned
    size_t base = (size_t)N * 33;
    base = (base + 3) & ~(size_t)3;       // align to 16B in floats
    uint4* pack = (uint4*)((float*)d_ws + base);
    size_t need = (base + (size_t)E * 4) * sizeof(float);
    bool haspack = ws_size >= need;

    const int BT = 256;
    const int EG = 2048;                   // grid-stride blocks for edge kernels
    const int node_grid = (N * 16 + BT - 1) / BT;

    // degree + basis pack (shared by all layers)
    hipMemsetAsync(deg, 0, (size_t)N * sizeof(float), stream);
    deg_count_kernel<<<2048, BT, 0, stream>>>(dst, deg, E);
    deg_inv_kernel<<<(N + BT - 1) / BT, BT, 0, stream>>>(deg, N);
    if (haspack)
        pack_kernel<<<2048, BT, 0, stream>>>(eattr, src, pack, E);

    // layer 1: x[N,2] -> hA
    hipMemsetAsync(hA, 0, (size_t)N * 16 * sizeof(float), stream);
    if (haspack)
        edge2_kernel<true><<<EG, BT, 0, stream>>>(x, dst, pack, eattr, src, W1, hA, E);
    else
        edge2_kernel<false><<<EG, BT, 0, stream>>>(x, dst, pack, eattr, src, W1, hA, E);
    finalize_kernel<2><<<node_grid, BT, 0, stream>>>(x, root1, b1, deg, hA, N);

    // layer 2: hA -> hB
    hipMemsetAsync(hB, 0, (size_t)N * 16 * sizeof(float), stream);
    if (haspack)
        edge16_kernel<true><<<EG, BT, 0, stream>>>(hA, dst, pack, eattr, src, W2, hB, E);
    else
        edge16_kernel<false><<<EG, BT, 0, stream>>>(hA, dst, pack, eattr, src, W2, hB, E);
    finalize_kernel<16><<<node_grid, BT, 0, stream>>>(hA, root2, b2, deg, hB, N);

    // layer 3: hB -> hA
    hipMemsetAsync(hA, 0, (size_t)N * 16 * sizeof(float), stream);
    if (haspack)
        edge16_kernel<true><<<EG, BT, 0, stream>>>(hB, dst, pack, eattr, src, W3, hA, E);
    else
        edge16_kernel<false><<<EG, BT, 0, stream>>>(hB, dst, pack, eattr, src, W3, hA, E);
    finalize_kernel<16><<<node_grid, BT, 0, stream>>>(hB, root3, b3, deg, hA, N);

    // final FC + sigmoid
    fc_kernel<<<(N + BT - 1) / BT, BT, 0, stream>>>(hA, fcw, fcb, out, N);
}

// Round 5
// 434.541 us; speedup vs baseline: 1.1613x; 1.1613x over previous
//
#include <hip/hip_runtime.h>
#include <math.h>

// ---------------------------------------------------------------------------
// SplineConv GNN: 3 layers (in=2->16, 16->16, 16->16), K=5 per dim (dim=2),
// degree-1 open B-spline, mean aggregation, root weight + bias, ReLU.
// Final: FC [16,1] + bias + sigmoid -> out[N] f32.
//
// Round 5: f16 weights in LDS + f16 activations in global, consumed by
// v_dot2_f32_f16 (packed 2-MAC, f32 accumulate) -> halves BOTH the LDS bytes
// (round-3 bound: 125us/CU) and the inner-loop VALU ops, with no unpack cost
// (round-4 lesson: bf16 shift/and unpack made it VALU-bound, 75% busy).
// LDS geometry identical to round 3's proven conflict-free layout
// (row = o*20 dwords, k stride 320 dwords; conflicts were 4.1e5 there vs
// 1.2e7 with round 4's o*12).
// Atomic mapping unchanged (16 threads/edge, channel-contiguous 64B lines).
// ---------------------------------------------------------------------------

#define KS 5

typedef _Float16 h2f __attribute__((ext_vector_type(2)));

__device__ __forceinline__ h2f u2h(unsigned u) { return __builtin_bit_cast(h2f, u); }

#if __has_builtin(__builtin_amdgcn_fdot2)
__device__ __forceinline__ float fdot2(h2f a, h2f b, float c) {
    return __builtin_amdgcn_fdot2(a, b, c, false);
}
#else
__device__ __forceinline__ float fdot2(h2f a, h2f b, float c) {
    return c + (float)a[0] * (float)b[0] + (float)a[1] * (float)b[1];
}
#endif

// ---- degree count -----------------------------------------------------------
__global__ void deg_count_kernel(const int* __restrict__ dst, float* __restrict__ deg, int E) {
    int stride = gridDim.x * blockDim.x;
    for (int e = blockIdx.x * blockDim.x + threadIdx.x; e < E; e += stride) {
        atomicAdd(&deg[dst[e]], 1.0f);
    }
}

__global__ void deg_inv_kernel(float* __restrict__ deg, int N) {
    int i = blockIdx.x * blockDim.x + threadIdx.x;
    if (i < N) deg[i] = 1.0f / fmaxf(deg[i], 1.0f);
}

// ---- per-edge basis precompute ---------------------------------------------
// pack = { wi0|wi1<<8|wi2<<16|wi3<<24, f32(f0), f32(f1), src }
__global__ void pack_kernel(const float* __restrict__ eattr, const int* __restrict__ src,
                            uint4* __restrict__ pack, int E) {
    int stride = gridDim.x * blockDim.x;
    for (int e = blockIdx.x * blockDim.x + threadIdx.x; e < E; e += stride) {
        float2 ea = reinterpret_cast<const float2*>(eattr)[e];
        float a0 = ea.x * (float)(KS - 1);
        float a1 = ea.y * (float)(KS - 1);
        float k0 = fminf(fmaxf(floorf(a0), 0.0f), (float)(KS - 2));
        float k1 = fminf(fmaxf(floorf(a1), 0.0f), (float)(KS - 2));
        float f0 = a0 - k0, f1 = a1 - k1;
        int i0 = (int)k0, i1 = (int)k1;
        int w00 = i0 + KS * i1;
        unsigned wis = (unsigned)w00 | ((unsigned)(w00 + 1) << 8) |
                       ((unsigned)(w00 + KS) << 16) | ((unsigned)(w00 + KS + 1) << 24);
        pack[e] = make_uint4(wis, __float_as_uint(f0), __float_as_uint(f1), (unsigned)src[e]);
    }
}

__device__ __forceinline__ void decode_or_compute(
        bool haspack, const uint4* pack, const float* eattr, const int* srcp,
        int e, int& s, float b[4], int wi[4]) {
    float f0, f1;
    if (haspack) {
        uint4 pk = pack[e];
        s = (int)pk.w;
        wi[0] = (int)(pk.x & 255); wi[1] = (int)((pk.x >> 8) & 255);
        wi[2] = (int)((pk.x >> 16) & 255); wi[3] = (int)(pk.x >> 24);
        f0 = __uint_as_float(pk.y);
        f1 = __uint_as_float(pk.z);
    } else {
        float2 ea = reinterpret_cast<const float2*>(eattr)[e];
        float a0 = ea.x * (float)(KS - 1);
        float a1 = ea.y * (float)(KS - 1);
        float k0 = fminf(fmaxf(floorf(a0), 0.0f), (float)(KS - 2));
        float k1 = fminf(fmaxf(floorf(a1), 0.0f), (float)(KS - 2));
        f0 = a0 - k0; f1 = a1 - k1;
        int i0 = (int)k0, i1 = (int)k1;
        int w00 = i0 + KS * i1;
        wi[0] = w00; wi[1] = w00 + 1; wi[2] = w00 + KS; wi[3] = w00 + KS + 1;
        s = srcp[e];
    }
    float g0 = 1.0f - f0, g1 = 1.0f - f1;
    b[0] = g0 * g1; b[1] = f0 * g1; b[2] = g0 * f1; b[3] = f0 * f1;
}

// ---- edge16: f16 h (global) x f16 W (LDS) via v_dot2_f32_f16 ---------------
// 16 threads per edge, o = t & 15. Grid-stride.
// LDS: dword row base = k*320 + o*20 (round-3 geometry), 8 dwords = 16 f16.
template <bool HASPACK>
__global__ __launch_bounds__(256) void edge16h_kernel(
        const ushort* __restrict__ hh,    // [N,16] f16
        const int* __restrict__ dst,
        const uint4* __restrict__ pack,   // [E] (if HASPACK)
        const float* __restrict__ eattr,  // [E,2] (if !HASPACK)
        const int* __restrict__ srcp,     // [E]   (if !HASPACK)
        const float* __restrict__ W,      // [25,16,16] f32
        float* __restrict__ agg,          // [N,16] zeroed
        int E) {
    __shared__ unsigned Wl[25 * 320];     // f16 pairs in low 8 dwords of each 20-dword row
    {
        ushort* Ws = reinterpret_cast<ushort*>(Wl);
        for (int idx = threadIdx.x; idx < 25 * 256; idx += blockDim.x) {
            int k = idx >> 8;
            int r = idx & 255;
            int i = r >> 4;
            int o = r & 15;
            Ws[(k * 320 + o * 20) * 2 + i] = __builtin_bit_cast(ushort, (_Float16)W[idx]);
        }
    }
    __syncthreads();

    int gs = gridDim.x * blockDim.x;
    int total = E * 16;
    for (int t = blockIdx.x * blockDim.x + threadIdx.x; t < total; t += gs) {
        int e = t >> 4;
        int o = t & 15;
        int s;
        float b[4];
        int wi[4];
        decode_or_compute(HASPACK, pack, eattr, srcp, e, s, b, wi);

        const uint4* hp = reinterpret_cast<const uint4*>(hh + (size_t)s * 16);
        uint4 ha = hp[0], hb = hp[1];

        float acc = 0.0f;
        #pragma unroll
        for (int sp = 0; sp < 4; ++sp) {
            const uint4* wp = reinterpret_cast<const uint4*>(&Wl[wi[sp] * 320 + o * 20]);
            uint4 wa = wp[0], wb = wp[1];
            float p = 0.0f;
            p = fdot2(u2h(ha.x), u2h(wa.x), p);
            p = fdot2(u2h(ha.y), u2h(wa.y), p);
            p = fdot2(u2h(ha.z), u2h(wa.z), p);
            p = fdot2(u2h(ha.w), u2h(wa.w), p);
            p = fdot2(u2h(hb.x), u2h(wb.x), p);
            p = fdot2(u2h(hb.y), u2h(wb.y), p);
            p = fdot2(u2h(hb.z), u2h(wb.z), p);
            p = fdot2(u2h(hb.w), u2h(wb.w), p);
            acc = fmaf(b[sp], p, acc);
        }
        atomicAdd(&agg[(size_t)dst[e] * 16 + o], acc);
    }
}

// ---- edge2: layer-1 (f32 x, tiny LDS) --------------------------------------
template <bool HASPACK>
__global__ __launch_bounds__(256) void edge2_kernel(
        const float* __restrict__ x,      // [N,2]
        const int* __restrict__ dst,
        const uint4* __restrict__ pack,
        const float* __restrict__ eattr,
        const int* __restrict__ srcp,
        const float* __restrict__ W,      // [25,2,16]
        float* __restrict__ agg,          // [N,16] zeroed
        int E) {
    // Wl[k][o][i] row stride 6 floats (24B, 8B-aligned), k stride 96 floats.
    __shared__ float Wl[25 * 96];
    for (int idx = threadIdx.x; idx < 25 * 32; idx += blockDim.x) {
        int k = idx >> 5;
        int r = idx & 31;
        int i = r >> 4;
        int o = r & 15;
        Wl[k * 96 + o * 6 + i] = W[idx];
    }
    __syncthreads();

    int gs = gridDim.x * blockDim.x;
    int total = E * 16;
    for (int t = blockIdx.x * blockDim.x + threadIdx.x; t < total; t += gs) {
        int e = t >> 4;
        int o = t & 15;
        int s;
        float b[4];
        int wi[4];
        decode_or_compute(HASPACK, pack, eattr, srcp, e, s, b, wi);

        float2 xv = reinterpret_cast<const float2*>(x)[s];

        float acc = 0.0f;
        #pragma unroll
        for (int sp = 0; sp < 4; ++sp) {
            float2 w = *reinterpret_cast<const float2*>(&Wl[wi[sp] * 96 + o * 6]);
            acc += b[sp] * (xv.x * w.x + xv.y * w.y);
        }
        atomicAdd(&agg[(size_t)dst[e] * 16 + o], acc);
    }
}

// ---- finalize layer 1: h16 = f16(relu(agg*invdeg + x@root + bias)) ---------
__global__ void finalize2h_kernel(const float* __restrict__ x,      // [N,2]
                                  const float* __restrict__ root,   // [2,16]
                                  const float* __restrict__ bias,   // [16]
                                  const float* __restrict__ invdeg, // [N]
                                  const float* __restrict__ agg,    // [N,16]
                                  ushort* __restrict__ hout,        // [N,16] f16
                                  int N) {
    int t = blockIdx.x * blockDim.x + threadIdx.x;
    if (t >= N * 16) return;
    int o = t & 15;
    int n = t >> 4;
    float2 xv = reinterpret_cast<const float2*>(x)[n];
    float acc = agg[t] * invdeg[n] + xv.x * root[o] + xv.y * root[16 + o] + bias[o];
    hout[t] = __builtin_bit_cast(ushort, (_Float16)fmaxf(acc, 0.0f));
}

// ---- finalize layers 2/3 ----------------------------------------------------
__global__ void finalize16h_kernel(const ushort* __restrict__ hin,   // [N,16] f16
                                   const float* __restrict__ root,   // [16,16]
                                   const float* __restrict__ bias,   // [16]
                                   const float* __restrict__ invdeg, // [N]
                                   const float* __restrict__ agg,    // [N,16]
                                   ushort* __restrict__ hout,        // [N,16] f16
                                   int N) {
    int t = blockIdx.x * blockDim.x + threadIdx.x;
    if (t >= N * 16) return;
    int o = t & 15;
    int n = t >> 4;
    const uint4* hp = reinterpret_cast<const uint4*>(hin + (size_t)n * 16);
    uint4 ha = hp[0], hb = hp[1];
    float acc = agg[t] * invdeg[n] + bias[o];
    unsigned dw[8] = {ha.x, ha.y, ha.z, ha.w, hb.x, hb.y, hb.z, hb.w};
    #pragma unroll
    for (int j = 0; j < 8; ++j) {
        h2f p = u2h(dw[j]);
        acc += (float)p[0] * root[(2 * j) * 16 + o] + (float)p[1] * root[(2 * j + 1) * 16 + o];
    }
    hout[t] = __builtin_bit_cast(ushort, (_Float16)fmaxf(acc, 0.0f));
}

// ---- final FC + sigmoid ----------------------------------------------------
__global__ void fc_kernel(const ushort* __restrict__ h,  // [N,16] f16
                          const float* __restrict__ fcw, // [16]
                          const float* __restrict__ fcb, // [1]
                          float* __restrict__ out, int N) {
    int n = blockIdx.x * blockDim.x + threadIdx.x;
    if (n >= N) return;
    const uint4* hp = reinterpret_cast<const uint4*>(h + (size_t)n * 16);
    uint4 ha = hp[0], hb = hp[1];
    unsigned dw[8] = {ha.x, ha.y, ha.z, ha.w, hb.x, hb.y, hb.z, hb.w};
    float acc = fcb[0];
    #pragma unroll
    for (int j = 0; j < 8; ++j) {
        h2f p = u2h(dw[j]);
        acc += (float)p[0] * fcw[2 * j] + (float)p[1] * fcw[2 * j + 1];
    }
    out[n] = 1.0f / (1.0f + expf(-acc));
}

extern "C" void kernel_launch(void* const* d_in, const int* in_sizes, int n_in,
                              void* d_out, int out_size, void* d_ws, size_t ws_size,
                              hipStream_t stream) {
    const float* x      = (const float*)d_in[0];   // [N,2]
    const int*   eidx   = (const int*)d_in[1];     // [2,E]
    const float* eattr  = (const float*)d_in[2];   // [E,2]
    const float* W1     = (const float*)d_in[3];
    const float* root1  = (const float*)d_in[4];
    const float* b1     = (const float*)d_in[5];
    const float* W2     = (const float*)d_in[6];
    const float* root2  = (const float*)d_in[7];
    const float* b2     = (const float*)d_in[8];
    const float* W3     = (const float*)d_in[9];
    const float* root3  = (const float*)d_in[10];
    const float* b3     = (const float*)d_in[11];
    const float* fcw    = (const float*)d_in[12];
    const float* fcb    = (const float*)d_in[13];
    float* out = (float*)d_out;

    const int N = in_sizes[0] / 2;
    const int E = in_sizes[2] / 2;
    const int* src = eidx;
    const int* dst = eidx + E;

    // workspace layout (float units):
    //   agg [N*16] | deg [N] | hH1 [N*8] | hH2 [N*8] | pack [E*4]
    float* agg = (float*)d_ws;
    float* deg = agg + (size_t)N * 16;
    size_t f17 = ((size_t)N * 17 + 3) & ~(size_t)3;
    ushort* hH1 = (ushort*)((float*)d_ws + f17);
    ushort* hH2 = hH1 + (size_t)N * 16;
    size_t packf = (f17 + (size_t)N * 16 + 3) & ~(size_t)3;
    uint4* pack = (uint4*)((float*)d_ws + packf);
    bool haspack = ws_size >= (packf + (size_t)E * 4) * sizeof(float);

    const int BT = 256;
    const int EG = 2048;                   // grid-stride blocks for edge kernels
    const int node_grid = (N * 16 + BT - 1) / BT;

    // degree + basis pack (shared by all layers)
    hipMemsetAsync(deg, 0, (size_t)N * sizeof(float), stream);
    deg_count_kernel<<<2048, BT, 0, stream>>>(dst, deg, E);
    deg_inv_kernel<<<(N + BT - 1) / BT, BT, 0, stream>>>(deg, N);
    if (haspack)
        pack_kernel<<<2048, BT, 0, stream>>>(eattr, src, pack, E);

    // layer 1: x[N,2] -> agg -> hH1 (f16)
    hipMemsetAsync(agg, 0, (size_t)N * 16 * sizeof(float), stream);
    if (haspack)
        edge2_kernel<true><<<EG, BT, 0, stream>>>(x, dst, pack, eattr, src, W1, agg, E);
    else
        edge2_kernel<false><<<EG, BT, 0, stream>>>(x, dst, pack, eattr, src, W1, agg, E);
    finalize2h_kernel<<<node_grid, BT, 0, stream>>>(x, root1, b1, deg, agg, hH1, N);

    // layer 2: hH1 -> agg -> hH2
    hipMemsetAsync(agg, 0, (size_t)N * 16 * sizeof(float), stream);
    if (haspack)
        edge16h_kernel<true><<<EG, BT, 0, stream>>>(hH1, dst, pack, eattr, src, W2, agg, E);
    else
        edge16h_kernel<false><<<EG, BT, 0, stream>>>(hH1, dst, pack, eattr, src, W2, agg, E);
    finalize16h_kernel<<<node_grid, BT, 0, stream>>>(hH1, root2, b2, deg, agg, hH2, N);

    // layer 3: hH2 -> agg -> hH1
    hipMemsetAsync(agg, 0, (size_t)N * 16 * sizeof(float), stream);
    if (haspack)
        edge16h_kernel<true><<<EG, BT, 0, stream>>>(hH2, dst, pack, eattr, src, W3, agg, E);
    else
        edge16h_kernel<false><<<EG, BT, 0, stream>>>(hH2, dst, pack, eattr, src, W3, agg, E);
    finalize16h_kernel<<<node_grid, BT, 0, stream>>>(hH2, root3, b3, deg, agg, hH1, N);

    // final FC + sigmoid
    fc_kernel<<<(N + BT - 1) / BT, BT, 0, stream>>>(hH1, fcw, fcb, out, N);
}